// Round 6
// baseline (118.130 us; speedup 1.0000x reference)
//
#include <hip/hip_runtime.h>
#include <cfloat>

// Problem constants (from reference)
#define Nn 32
#define Qq 300
#define Cc 92
#define Tt 32
#define KCOLS 5     // ceil(300/64) columns owned per lane
#define LSTRIDE 93  // LDS logits row stride (dwords); 93%32=29 coprime -> conflict-free

// ---------------------------------------------------------------------------
// DPP full-wave (64-lane) float min, broadcast to all lanes (~6 dep. v_min).
// ---------------------------------------------------------------------------
__device__ inline float wave_min_bcast(float x) {
#define DPPMIN(ctrl) { int _t = __builtin_amdgcn_update_dpp( \
        __float_as_int(x), __float_as_int(x), ctrl, 0xf, 0xf, false); \
        x = fminf(x, __int_as_float(_t)); }
    DPPMIN(0x111) DPPMIN(0x112) DPPMIN(0x114) DPPMIN(0x118)
    DPPMIN(0x142) DPPMIN(0x143)
#undef DPPMIN
    return __int_as_float(__builtin_amdgcn_readlane(__float_as_int(x), 63));
}

// Select a[k] for runtime k (cndmask chain, no scratch).
__device__ inline int sel5i(const int a[KCOLS], int k) {
    int r = a[0];
    if (k == 1) r = a[1];
    if (k == 2) r = a[2];
    if (k == 3) r = a[3];
    if (k == 4) r = a[4];
    return r;
}

__device__ inline float readlane_f(float v, int lane) {
    return __int_as_float(__builtin_amdgcn_readlane(__float_as_int(v), lane));
}

// Softmax stats over C=92 from LDS row (stride LSTRIDE). SAME code path for
// phase A and phase C so mx/inv_s match bit-for-bit.
__device__ inline void softmax_lds(const float* __restrict__ srow,
                                   float& mx, float& inv_s) {
    float lv[Cc];
#pragma unroll
    for (int c = 0; c < Cc; ++c) lv[c] = srow[c];
    float m = -FLT_MAX;
#pragma unroll
    for (int c = 0; c < Cc; ++c) m = fmaxf(m, lv[c]);
    float s = 0.f;
#pragma unroll
    for (int c = 0; c < Cc; ++c) s += __expf(lv[c] - m);
    mx = m; inv_s = 1.f / s;
}

// cost = 5*L1 + cls - 2*giou   (cls = -softmax_prob[label], passed in)
__device__ inline float det_cost(float cx, float cy, float w, float h,
                                 float bcx, float bcy, float bw, float bh,
                                 float cls) {
    const float ax0 = cx - 0.5f * w, ay0 = cy - 0.5f * h;
    const float ax1 = cx + 0.5f * w, ay1 = cy + 0.5f * h;
    const float areaA = (ax1 - ax0) * (ay1 - ay0);

    const float l1 = fabsf(cx - bcx) + fabsf(cy - bcy) +
                     fabsf(w - bw) + fabsf(h - bh);

    const float bx0 = bcx - 0.5f * bw, by0 = bcy - 0.5f * bh;
    const float bx1 = bcx + 0.5f * bw, by1 = bcy + 0.5f * bh;
    const float areaB = (bx1 - bx0) * (by1 - by0);

    const float ltx = fmaxf(ax0, bx0), lty = fmaxf(ay0, by0);
    const float rbx = fminf(ax1, bx1), rby = fminf(ay1, by1);
    const float iw = fmaxf(rbx - ltx, 0.f), ih = fmaxf(rby - lty, 0.f);
    const float inter = iw * ih;
    const float uni = areaA + areaB - inter;
    const float iou = inter / uni;

    const float ex0 = fminf(ax0, bx0), ey0 = fminf(ay0, by0);
    const float ex1 = fmaxf(ax1, bx1), ey1 = fmaxf(ay1, by1);
    const float areaC = fmaxf(ex1 - ex0, 0.f) * fmaxf(ey1 - ey0, 0.f);
    const float giou = iou - (areaC - uni) / areaC;

    return 5.f * l1 + cls - 2.f * giou;
}

// ---------------------------------------------------------------------------
// Fused kernel: one block per batch.
//  Phase 0 (320 threads): stage batch's logits slice (110 KB) into LDS via
//    DENSE COALESCED float4 loads (fixes the cold-gather HBM-latency wall:
//    368-B-strided lane access = 64 cold lines/instruction, ~45 us of stall).
//  Phase A (320 threads): diag cost block -> LDS (softmax reads LDS).
//  Phase B (wave 0): deferred-dual JV LSA; column state in registers,
//    u in lane-registers, cross-lane via readlane (uniform idx).
//  Phase C (lanes 0-31): 32 matched CROSS costs (reference quirk:
//    mult[i, q_of_t, arange(T)] gathers against GLOBAL targets 0..31).
// ---------------------------------------------------------------------------
__global__ __launch_bounds__(320) void fused_kernel(
    const float* __restrict__ logits,   // [N,Q,C]
    const float* __restrict__ pboxes,   // [N,Q,4]
    const int*   __restrict__ tlabels,  // [N*T]
    const float* __restrict__ tboxes,   // [N*T,4]
    float* __restrict__ out)            // scalar accumulator (pre-zeroed)
{
    const int b = blockIdx.x;
    const int tid = threadIdx.x;

    extern __shared__ float s_lg[];     // [Qq][LSTRIDE] padded logits, 111600 B
    __shared__ float s_diag[Tt * Qq];   // 38400 B, [t][q]
    __shared__ float s_tb[Tt * 4];      // batch-b targets
    __shared__ int   s_tl[Tt];
    __shared__ float dm_lds[Tt + 1];    // per-row dual-update staging
    __shared__ int   pairs[Tt];         // q_of_t

    if (tid < Tt * 4) s_tb[tid] = tboxes[b * Tt * 4 + tid];
    if (tid < Tt)     s_tl[tid] = tlabels[b * Tt + tid];

    // ---------------- Phase 0: coalesced logits -> LDS ----------------
    // 92 floats/row = exactly 23 float4 granules; granule g -> row g/23,
    // dword col 4*(g%23). Dense linear global order -> full miss pipelining.
    {
        const float4* lgb = reinterpret_cast<const float4*>(
            logits + (size_t)b * Qq * Cc);
        for (int g = tid; g < Qq * 23; g += 320) {
            const float4 v = lgb[g];
            const int r = g / 23, c4 = (g - r * 23) * 4;
            float* dst = &s_lg[r * LSTRIDE + c4];
            dst[0] = v.x; dst[1] = v.y; dst[2] = v.z; dst[3] = v.w;
        }
    }
    __syncthreads();

    // ---------------- Phase A: diag costs into LDS ----------------
    if (tid < Qq) {
        const float* srow = &s_lg[tid * LSTRIDE];
        float mx, inv_s;
        softmax_lds(srow, mx, inv_s);
        const float4 pbv = reinterpret_cast<const float4*>(pboxes)[b * Qq + tid];
#pragma unroll 4
        for (int t = 0; t < Tt; ++t) {
            const float cls = -__expf(srow[s_tl[t]] - mx) * inv_s;
            s_diag[t * Qq + tid] =
                det_cost(pbv.x, pbv.y, pbv.z, pbv.w,
                         s_tb[t * 4 + 0], s_tb[t * 4 + 1],
                         s_tb[t * 4 + 2], s_tb[t * 4 + 3], cls);
        }
    }
    __syncthreads();      // all 320 threads reach this

    if (tid >= 64) return;            // waves 1-4 done; single wave below
    const int lane = tid;

    // ---------------- Phase B: JV LSA (single wave) ----------------
    float u_reg = 0.f;                // lane t holds u[t] (t=1..32)
    float v_r[KCOLS], minv_r[KCOLS];
    int way_r[KCOLS], p_r[KCOLS], used_r[KCOLS];
    const int inval4 = (lane + 256) >= Qq;   // only k=4 can be out of range
#pragma unroll
    for (int k = 0; k < KCOLS; ++k) { v_r[k] = 0.f; p_r[k] = 0; }

    for (int i = 1; i <= Tt; ++i) {
#pragma unroll
        for (int k = 0; k < KCOLS; ++k) {
            minv_r[k] = FLT_MAX; way_r[k] = 0;
            used_r[k] = (k == 4) ? inval4 : 0;
        }

        int   j0 = 0;
        int   i0 = i;
        float du = 0.f;          // dent - u[i0]; u[i]==0 for the fresh row
        int   jfinal = 0;
        float Dfinal = 0.f;

        while (true) {
            // scan free columns; update minv; local candidate
            float val = FLT_MAX;
            int idx = 0, kb = 0;
            const int rowbase = (i0 - 1) * Qq;
#pragma unroll
            for (int k = 0; k < KCOLS; ++k) {
                if (!used_r[k]) {
                    const int j = lane + 64 * k;
                    const float cur = s_diag[rowbase + j] + du - v_r[k];
                    if (cur < minv_r[k]) { minv_r[k] = cur; way_r[k] = j0; }
                    if (minv_r[k] < val) { val = minv_r[k]; idx = j + 1; kb = k; }
                }
            }
            // wave argmin; winner's (matched row, col) via one 32-bit readlane
            const float gmin = wave_min_bcast(val);
            const unsigned long long mask = __ballot(val == gmin);
            const int src = __ffsll((long long)mask) - 1;
            const int pk = (sel5i(p_r, kb) << 16) | idx;      // row<=32, col<=300
            const int got = __builtin_amdgcn_readlane(pk, src);
            const int j1   = got & 0xffff;
            const int rowm = got >> 16;

            // mark j1 used at its owner lane
            const int k1 = (j1 - 1) >> 6;
            const bool own = (lane == ((j1 - 1) & 63));
#pragma unroll
            for (int k = 0; k < KCOLS; ++k) if (own && k == k1) used_r[k] = 1;

            if (rowm == 0) { jfinal = j1; Dfinal = gmin; break; }
            j0 = j1; i0 = rowm;
            du = gmin - readlane_f(u_reg, i0);   // dent - u[i0], register-speed
        }

        // ---- dual updates, once per row (off the critical inner loop) ----
        if (lane <= Tt) dm_lds[lane] = 0.f;
        __threadfence_block();
#pragma unroll
        for (int k = 0; k < KCOLS; ++k) {
            if (used_r[k]) {
                const float dm = Dfinal - minv_r[k];
                v_r[k] -= dm;
                dm_lds[p_r[k]] = dm;   // distinct rows; jfinal scatters dm=0 to slot 0
            }
        }
        __threadfence_block();
        if (lane <= Tt) u_reg += (lane == i) ? Dfinal : dm_lds[lane];

        // ---- augment along the path (readlane walk; usually 1 hop) ----
        int jj = jfinal;
        while (jj) {
            const int ow = (jj - 1) & 63, kk = (jj - 1) >> 6;
            const int jprev = __builtin_amdgcn_readlane(sel5i(way_r, kk), ow);
            int pnew;
            if (jprev == 0) pnew = i;
            else pnew = __builtin_amdgcn_readlane(sel5i(p_r, (jprev - 1) >> 6),
                                                  (jprev - 1) & 63);
            const bool own = (lane == ow);
#pragma unroll
            for (int k = 0; k < KCOLS; ++k) if (own && k == kk) p_r[k] = pnew;
            jj = jprev;
        }
    }

    // publish assignment: q_of_t
#pragma unroll
    for (int k = 0; k < KCOLS; ++k)
        if (p_r[k]) pairs[p_r[k] - 1] = lane + 64 * k;
    __threadfence_block();

    // ---------------- Phase C: 32 matched cross costs ----------------
    float part = 0.f;
    if (lane < Tt) {
        const int q = pairs[lane];                        // matched query
        const float* srow = &s_lg[q * LSTRIDE];
        float mx, inv_s;
        softmax_lds(srow, mx, inv_s);                      // identical path to phase A
        const float4 pbv = reinterpret_cast<const float4*>(pboxes)[b * Qq + q];
        const float4 tbv = reinterpret_cast<const float4*>(tboxes)[lane];  // GLOBAL t=lane
        const float cls = -__expf(srow[tlabels[lane]] - mx) * inv_s;
        part = det_cost(pbv.x, pbv.y, pbv.z, pbv.w,
                        tbv.x, tbv.y, tbv.z, tbv.w, cls);
    }
    for (int off = 32; off > 0; off >>= 1) part += __shfl_down(part, off);
    if (lane == 0) atomicAdd(out, part);
}

extern "C" void kernel_launch(void* const* d_in, const int* in_sizes, int n_in,
                              void* d_out, int out_size, void* d_ws, size_t ws_size,
                              hipStream_t stream) {
    const float* logits  = (const float*)d_in[0];   // [32,300,92] f32
    const float* pboxes  = (const float*)d_in[1];   // [32,300,4]  f32
    const int*   tlabels = (const int*)d_in[2];     // [1024]      int
    const float* tboxes  = (const float*)d_in[3];   // [1024,4]    f32
    float* out = (float*)d_out;                     // scalar f32

    hipMemsetAsync(out, 0, sizeof(float), stream);
    const size_t lg_bytes = (size_t)Qq * LSTRIDE * sizeof(float);  // 111600 B
    fused_kernel<<<Nn, 320, lg_bytes, stream>>>(logits, pboxes, tlabels, tboxes, out);
}

// Round 7
// 113.704 us; speedup vs baseline: 1.0389x; 1.0389x over previous
//
#include <hip/hip_runtime.h>
#include <cfloat>

// Problem constants (from reference)
#define Nn 32
#define Qq 300
#define Cc 92
#define Tt 32
#define KCOLS 5     // ceil(300/64) columns owned per lane
#define LSTRIDE 93  // LDS logits row stride (dwords); 93%32=29 coprime -> conflict-free

// ---------------------------------------------------------------------------
// DPP full-wave (64-lane) float min, broadcast to all lanes (~6 dep. v_min).
// ---------------------------------------------------------------------------
__device__ inline float wave_min_bcast(float x) {
#define DPPMIN(ctrl) { int _t = __builtin_amdgcn_update_dpp( \
        __float_as_int(x), __float_as_int(x), ctrl, 0xf, 0xf, false); \
        x = fminf(x, __int_as_float(_t)); }
    DPPMIN(0x111) DPPMIN(0x112) DPPMIN(0x114) DPPMIN(0x118)
    DPPMIN(0x142) DPPMIN(0x143)
#undef DPPMIN
    return __int_as_float(__builtin_amdgcn_readlane(__float_as_int(x), 63));
}

// Select a[k] for runtime k (cndmask chain, no scratch).
__device__ inline int sel5i(const int a[KCOLS], int k) {
    int r = a[0];
    if (k == 1) r = a[1];
    if (k == 2) r = a[2];
    if (k == 3) r = a[3];
    if (k == 4) r = a[4];
    return r;
}

__device__ inline float readlane_f(float v, int lane) {
    return __int_as_float(__builtin_amdgcn_readlane(__float_as_int(v), lane));
}

// STREAMING two-pass softmax over an LDS row — NO 92-element register array
// (the r3-r6 versions spilled ~92 floats/thread to scratch: VGPR_Count 48-64
// cannot hold them; that scratch round-trip was the real phase-A/C wall).
// 4 partial exp-sums break the 92-long dependent add chain. Same helper used
// in phase A and phase C so mx/inv_s match bit-for-bit.
__device__ inline void softmax_lds(const float* __restrict__ srow,
                                   float& mx, float& inv_s) {
    float m = -FLT_MAX;
#pragma unroll
    for (int c = 0; c < Cc; ++c) m = fmaxf(m, srow[c]);
    float s0 = 0.f, s1 = 0.f, s2 = 0.f, s3 = 0.f;
#pragma unroll
    for (int c = 0; c < Cc; c += 4) {
        s0 += __expf(srow[c + 0] - m);
        s1 += __expf(srow[c + 1] - m);
        s2 += __expf(srow[c + 2] - m);
        s3 += __expf(srow[c + 3] - m);
    }
    mx = m; inv_s = 1.f / ((s0 + s1) + (s2 + s3));
}

// cost = 5*L1 + cls - 2*giou   (cls = -softmax_prob[label], passed in)
__device__ inline float det_cost(float cx, float cy, float w, float h,
                                 float bcx, float bcy, float bw, float bh,
                                 float cls) {
    const float ax0 = cx - 0.5f * w, ay0 = cy - 0.5f * h;
    const float ax1 = cx + 0.5f * w, ay1 = cy + 0.5f * h;
    const float areaA = (ax1 - ax0) * (ay1 - ay0);

    const float l1 = fabsf(cx - bcx) + fabsf(cy - bcy) +
                     fabsf(w - bw) + fabsf(h - bh);

    const float bx0 = bcx - 0.5f * bw, by0 = bcy - 0.5f * bh;
    const float bx1 = bcx + 0.5f * bw, by1 = bcy + 0.5f * bh;
    const float areaB = (bx1 - bx0) * (by1 - by0);

    const float ltx = fmaxf(ax0, bx0), lty = fmaxf(ay0, by0);
    const float rbx = fminf(ax1, bx1), rby = fminf(ay1, by1);
    const float iw = fmaxf(rbx - ltx, 0.f), ih = fmaxf(rby - lty, 0.f);
    const float inter = iw * ih;
    const float uni = areaA + areaB - inter;
    const float iou = inter / uni;

    const float ex0 = fminf(ax0, bx0), ey0 = fminf(ay0, by0);
    const float ex1 = fmaxf(ax1, bx1), ey1 = fmaxf(ay1, by1);
    const float areaC = fmaxf(ex1 - ex0, 0.f) * fmaxf(ey1 - ey0, 0.f);
    const float giou = iou - (areaC - uni) / areaC;

    return 5.f * l1 + cls - 2.f * giou;
}

// ---------------------------------------------------------------------------
// Fused kernel: one block per batch.
//  Phase 0 (320 threads): stage batch's logits slice (110 KB) -> LDS, dense
//    coalesced float4 loads, unroll x4 for miss pipelining.
//  Phase A (320 threads): diag cost block -> LDS (streaming softmax, no spill).
//  Phase B (wave 0): deferred-dual JV LSA; column state in registers,
//    u in lane-registers, cross-lane via readlane (uniform idx).
//  Phase C (lanes 0-31): 32 matched CROSS costs (reference quirk:
//    mult[i, q_of_t, arange(T)] gathers against GLOBAL targets 0..31).
// ---------------------------------------------------------------------------
__global__ __launch_bounds__(320) void fused_kernel(
    const float* __restrict__ logits,   // [N,Q,C]
    const float* __restrict__ pboxes,   // [N,Q,4]
    const int*   __restrict__ tlabels,  // [N*T]
    const float* __restrict__ tboxes,   // [N*T,4]
    float* __restrict__ out)            // scalar accumulator (pre-zeroed)
{
    const int b = blockIdx.x;
    const int tid = threadIdx.x;

    extern __shared__ float s_lg[];     // [Qq][LSTRIDE] padded logits, 111600 B
    __shared__ float s_diag[Tt * Qq];   // 38400 B, [t][q]
    __shared__ float s_tb[Tt * 4];      // batch-b targets
    __shared__ int   s_tl[Tt];
    __shared__ float dm_lds[Tt + 1];    // per-row dual-update staging
    __shared__ int   pairs[Tt];         // q_of_t

    if (tid < Tt * 4) s_tb[tid] = tboxes[b * Tt * 4 + tid];
    if (tid < Tt)     s_tl[tid] = tlabels[b * Tt + tid];

    // ---------------- Phase 0: coalesced logits -> LDS ----------------
    // 92 floats/row = exactly 23 float4 granules; granule g -> row g/23,
    // dword col 4*(g%23). Unroll x4 keeps 4 misses in flight.
    {
        const float4* lgb = reinterpret_cast<const float4*>(
            logits + (size_t)b * Qq * Cc);
#pragma unroll 4
        for (int g = tid; g < Qq * 23; g += 320) {
            const float4 v = lgb[g];
            const int r = g / 23, c4 = (g - r * 23) * 4;
            float* dst = &s_lg[r * LSTRIDE + c4];
            dst[0] = v.x; dst[1] = v.y; dst[2] = v.z; dst[3] = v.w;
        }
    }
    __syncthreads();

    // ---------------- Phase A: diag costs into LDS ----------------
    if (tid < Qq) {
        const float* srow = &s_lg[tid * LSTRIDE];
        float mx, inv_s;
        softmax_lds(srow, mx, inv_s);
        const float4 pbv = reinterpret_cast<const float4*>(pboxes)[b * Qq + tid];
#pragma unroll 4
        for (int t = 0; t < Tt; ++t) {
            const float cls = -__expf(srow[s_tl[t]] - mx) * inv_s;
            s_diag[t * Qq + tid] =
                det_cost(pbv.x, pbv.y, pbv.z, pbv.w,
                         s_tb[t * 4 + 0], s_tb[t * 4 + 1],
                         s_tb[t * 4 + 2], s_tb[t * 4 + 3], cls);
        }
    }
    __syncthreads();      // all 320 threads reach this

    if (tid >= 64) return;            // waves 1-4 done; single wave below
    const int lane = tid;

    // ---------------- Phase B: JV LSA (single wave) ----------------
    float u_reg = 0.f;                // lane t holds u[t] (t=1..32)
    float v_r[KCOLS], minv_r[KCOLS];
    int way_r[KCOLS], p_r[KCOLS], used_r[KCOLS];
    const int inval4 = (lane + 256) >= Qq;   // only k=4 can be out of range
#pragma unroll
    for (int k = 0; k < KCOLS; ++k) { v_r[k] = 0.f; p_r[k] = 0; }

    for (int i = 1; i <= Tt; ++i) {
#pragma unroll
        for (int k = 0; k < KCOLS; ++k) {
            minv_r[k] = FLT_MAX; way_r[k] = 0;
            used_r[k] = (k == 4) ? inval4 : 0;
        }

        int   j0 = 0;
        int   i0 = i;
        float du = 0.f;          // dent - u[i0]; u[i]==0 for the fresh row
        int   jfinal = 0;
        float Dfinal = 0.f;

        while (true) {
            // scan free columns; update minv; local candidate
            float val = FLT_MAX;
            int idx = 0, kb = 0;
            const int rowbase = (i0 - 1) * Qq;
#pragma unroll
            for (int k = 0; k < KCOLS; ++k) {
                if (!used_r[k]) {
                    const int j = lane + 64 * k;
                    const float cur = s_diag[rowbase + j] + du - v_r[k];
                    if (cur < minv_r[k]) { minv_r[k] = cur; way_r[k] = j0; }
                    if (minv_r[k] < val) { val = minv_r[k]; idx = j + 1; kb = k; }
                }
            }
            // wave argmin; winner's (matched row, col) via one 32-bit readlane
            const float gmin = wave_min_bcast(val);
            const unsigned long long mask = __ballot(val == gmin);
            const int src = __ffsll((long long)mask) - 1;
            const int pk = (sel5i(p_r, kb) << 16) | idx;      // row<=32, col<=300
            const int got = __builtin_amdgcn_readlane(pk, src);
            const int j1   = got & 0xffff;
            const int rowm = got >> 16;

            // mark j1 used at its owner lane
            const int k1 = (j1 - 1) >> 6;
            const bool own = (lane == ((j1 - 1) & 63));
#pragma unroll
            for (int k = 0; k < KCOLS; ++k) if (own && k == k1) used_r[k] = 1;

            if (rowm == 0) { jfinal = j1; Dfinal = gmin; break; }
            j0 = j1; i0 = rowm;
            du = gmin - readlane_f(u_reg, i0);   // dent - u[i0], register-speed
        }

        // ---- dual updates, once per row (off the critical inner loop) ----
        if (lane <= Tt) dm_lds[lane] = 0.f;
        __threadfence_block();
#pragma unroll
        for (int k = 0; k < KCOLS; ++k) {
            if (used_r[k]) {
                const float dm = Dfinal - minv_r[k];
                v_r[k] -= dm;
                dm_lds[p_r[k]] = dm;   // distinct rows; jfinal scatters dm=0 to slot 0
            }
        }
        __threadfence_block();
        if (lane <= Tt) u_reg += (lane == i) ? Dfinal : dm_lds[lane];

        // ---- augment along the path (readlane walk; usually 1 hop) ----
        int jj = jfinal;
        while (jj) {
            const int ow = (jj - 1) & 63, kk = (jj - 1) >> 6;
            const int jprev = __builtin_amdgcn_readlane(sel5i(way_r, kk), ow);
            int pnew;
            if (jprev == 0) pnew = i;
            else pnew = __builtin_amdgcn_readlane(sel5i(p_r, (jprev - 1) >> 6),
                                                  (jprev - 1) & 63);
            const bool own = (lane == ow);
#pragma unroll
            for (int k = 0; k < KCOLS; ++k) if (own && k == kk) p_r[k] = pnew;
            jj = jprev;
        }
    }

    // publish assignment: q_of_t
#pragma unroll
    for (int k = 0; k < KCOLS; ++k)
        if (p_r[k]) pairs[p_r[k] - 1] = lane + 64 * k;
    __threadfence_block();

    // ---------------- Phase C: 32 matched cross costs ----------------
    float part = 0.f;
    if (lane < Tt) {
        const int q = pairs[lane];                        // matched query
        const float* srow = &s_lg[q * LSTRIDE];
        float mx, inv_s;
        softmax_lds(srow, mx, inv_s);                      // identical path to phase A
        const float4 pbv = reinterpret_cast<const float4*>(pboxes)[b * Qq + q];
        const float4 tbv = reinterpret_cast<const float4*>(tboxes)[lane];  // GLOBAL t=lane
        const float cls = -__expf(srow[tlabels[lane]] - mx) * inv_s;
        part = det_cost(pbv.x, pbv.y, pbv.z, pbv.w,
                        tbv.x, tbv.y, tbv.z, tbv.w, cls);
    }
    for (int off = 32; off > 0; off >>= 1) part += __shfl_down(part, off);
    if (lane == 0) atomicAdd(out, part);
}

extern "C" void kernel_launch(void* const* d_in, const int* in_sizes, int n_in,
                              void* d_out, int out_size, void* d_ws, size_t ws_size,
                              hipStream_t stream) {
    const float* logits  = (const float*)d_in[0];   // [32,300,92] f32
    const float* pboxes  = (const float*)d_in[1];   // [32,300,4]  f32
    const int*   tlabels = (const int*)d_in[2];     // [1024]      int
    const float* tboxes  = (const float*)d_in[3];   // [1024,4]    f32
    float* out = (float*)d_out;                     // scalar f32

    hipMemsetAsync(out, 0, sizeof(float), stream);
    const size_t lg_bytes = (size_t)Qq * LSTRIDE * sizeof(float);  // 111600 B
    fused_kernel<<<Nn, 320, lg_bytes, stream>>>(logits, pboxes, tlabels, tboxes, out);
}

// Round 8
// 100.590 us; speedup vs baseline: 1.1744x; 1.1304x over previous
//
#include <hip/hip_runtime.h>
#include <cfloat>
#include <cmath>

// Problem constants (from reference)
#define Nn 32
#define Qq 300
#define Cc 92
#define Tt 32
#define KCOLS 5     // ceil(300/64) columns owned per lane
#define LSTRIDE 93  // LDS logits row stride (dwords); 93%32=29 coprime -> conflict-free

// ---------------------------------------------------------------------------
// DPP full-wave (64-lane) float min, broadcast to all lanes (~6 dep. v_min).
// ---------------------------------------------------------------------------
__device__ inline float wave_min_bcast(float x) {
#define DPPMIN(ctrl) { int _t = __builtin_amdgcn_update_dpp( \
        __float_as_int(x), __float_as_int(x), ctrl, 0xf, 0xf, false); \
        x = fminf(x, __int_as_float(_t)); }
    DPPMIN(0x111) DPPMIN(0x112) DPPMIN(0x114) DPPMIN(0x118)
    DPPMIN(0x142) DPPMIN(0x143)
#undef DPPMIN
    return __int_as_float(__builtin_amdgcn_readlane(__float_as_int(x), 63));
}

// Select a[k] for runtime k (cndmask chain, no scratch).
__device__ inline int sel5i(const int a[KCOLS], int k) {
    int r = a[0];
    if (k == 1) r = a[1];
    if (k == 2) r = a[2];
    if (k == 3) r = a[3];
    if (k == 4) r = a[4];
    return r;
}

__device__ inline float readlane_f(float v, int lane) {
    return __int_as_float(__builtin_amdgcn_readlane(__float_as_int(v), lane));
}

// STREAMING two-pass softmax over an LDS row (no 92-float register array ->
// no scratch spill). Same helper in phase A and C: mx/inv_s bit-identical.
__device__ inline void softmax_lds(const float* __restrict__ srow,
                                   float& mx, float& inv_s) {
    float m = -FLT_MAX;
#pragma unroll
    for (int c = 0; c < Cc; ++c) m = fmaxf(m, srow[c]);
    float s0 = 0.f, s1 = 0.f, s2 = 0.f, s3 = 0.f;
#pragma unroll
    for (int c = 0; c < Cc; c += 4) {
        s0 += __expf(srow[c + 0] - m);
        s1 += __expf(srow[c + 1] - m);
        s2 += __expf(srow[c + 2] - m);
        s3 += __expf(srow[c + 3] - m);
    }
    mx = m; inv_s = 1.f / ((s0 + s1) + (s2 + s3));
}

// cost = 5*L1 + cls - 2*giou   (cls = -softmax_prob[label], passed in)
__device__ inline float det_cost(float cx, float cy, float w, float h,
                                 float bcx, float bcy, float bw, float bh,
                                 float cls) {
    const float ax0 = cx - 0.5f * w, ay0 = cy - 0.5f * h;
    const float ax1 = cx + 0.5f * w, ay1 = cy + 0.5f * h;
    const float areaA = (ax1 - ax0) * (ay1 - ay0);

    const float l1 = fabsf(cx - bcx) + fabsf(cy - bcy) +
                     fabsf(w - bw) + fabsf(h - bh);

    const float bx0 = bcx - 0.5f * bw, by0 = bcy - 0.5f * bh;
    const float bx1 = bcx + 0.5f * bw, by1 = bcy + 0.5f * bh;
    const float areaB = (bx1 - bx0) * (by1 - by0);

    const float ltx = fmaxf(ax0, bx0), lty = fmaxf(ay0, by0);
    const float rbx = fminf(ax1, bx1), rby = fminf(ay1, by1);
    const float iw = fmaxf(rbx - ltx, 0.f), ih = fmaxf(rby - lty, 0.f);
    const float inter = iw * ih;
    const float uni = areaA + areaB - inter;
    const float iou = inter / uni;

    const float ex0 = fminf(ax0, bx0), ey0 = fminf(ay0, by0);
    const float ex1 = fmaxf(ax1, bx1), ey1 = fmaxf(ay1, by1);
    const float areaC = fmaxf(ex1 - ex0, 0.f) * fmaxf(ey1 - ey0, 0.f);
    const float giou = iou - (areaC - uni) / areaC;

    return 5.f * l1 + cls - 2.f * giou;
}

// ---------------------------------------------------------------------------
// Fused kernel: one block per batch.
//  Phase 0: stage logits slice -> LDS (dense coalesced float4).
//  Phase A: diag cost block -> LDS (streaming softmax).
//  Phase B (wave 0): deferred-dual JV LSA. Evidence (r2-r7) says ~300
//    Dijkstra steps/batch, latency-bound. This round: BRANCHLESS scan
//    (used/invalid columns masked via vmask=-inf -> cur=+inf freeze, and
//    am=+inf -> excluded from argmin), NEXT-ROW LDS PREFETCH right after the
//    winner readlane, and a zero-LDS row tail (markg/ent per-lane tracking
//    replaces the dm_lds scatter + two fences).
//  Phase C (lanes 0-31): 32 matched CROSS costs (reference quirk:
//    mult[i, q_of_t, arange(T)] gathers against GLOBAL targets 0..31).
// ---------------------------------------------------------------------------
__global__ __launch_bounds__(320) void fused_kernel(
    const float* __restrict__ logits,   // [N,Q,C]
    const float* __restrict__ pboxes,   // [N,Q,4]
    const int*   __restrict__ tlabels,  // [N*T]
    const float* __restrict__ tboxes,   // [N*T,4]
    float* __restrict__ out)            // scalar accumulator (pre-zeroed)
{
    const int b = blockIdx.x;
    const int tid = threadIdx.x;

    extern __shared__ float s_lg[];     // [Qq][LSTRIDE] padded logits, 111600 B
    __shared__ float s_diag[Tt * Qq];   // 38400 B, [t][q]
    __shared__ float s_tb[Tt * 4];      // batch-b targets
    __shared__ int   s_tl[Tt];
    __shared__ int   pairs[Tt];         // q_of_t

    if (tid < Tt * 4) s_tb[tid] = tboxes[b * Tt * 4 + tid];
    if (tid < Tt)     s_tl[tid] = tlabels[b * Tt + tid];

    // ---------------- Phase 0: coalesced logits -> LDS ----------------
    {
        const float4* lgb = reinterpret_cast<const float4*>(
            logits + (size_t)b * Qq * Cc);
#pragma unroll 4
        for (int g = tid; g < Qq * 23; g += 320) {
            const float4 v = lgb[g];
            const int r = g / 23, c4 = (g - r * 23) * 4;
            float* dst = &s_lg[r * LSTRIDE + c4];
            dst[0] = v.x; dst[1] = v.y; dst[2] = v.z; dst[3] = v.w;
        }
    }
    __syncthreads();

    // ---------------- Phase A: diag costs into LDS ----------------
    if (tid < Qq) {
        const float* srow = &s_lg[tid * LSTRIDE];
        float mx, inv_s;
        softmax_lds(srow, mx, inv_s);
        const float4 pbv = reinterpret_cast<const float4*>(pboxes)[b * Qq + tid];
#pragma unroll 4
        for (int t = 0; t < Tt; ++t) {
            const float cls = -__expf(srow[s_tl[t]] - mx) * inv_s;
            s_diag[t * Qq + tid] =
                det_cost(pbv.x, pbv.y, pbv.z, pbv.w,
                         s_tb[t * 4 + 0], s_tb[t * 4 + 1],
                         s_tb[t * 4 + 2], s_tb[t * 4 + 3], cls);
        }
    }
    __syncthreads();      // all 320 threads reach this

    if (tid >= 64) return;            // waves 1-4 done; single wave below
    const int lane = tid;

    // ---------------- Phase B: JV LSA (single wave) ----------------
    float u_reg = 0.f;                // lane t holds u[t] (t=1..32)
    float v_r[KCOLS], minv_r[KCOLS];
    int way_r[KCOLS], p_r[KCOLS];
    const bool inval4 = (lane + 256) >= Qq;   // only k=4 can be out of range
#pragma unroll
    for (int k = 0; k < KCOLS; ++k) { v_r[k] = 0.f; p_r[k] = 0; }

    for (int i = 1; i <= Tt; ++i) {
        float vmask[KCOLS], am[KCOLS];
#pragma unroll
        for (int k = 0; k < KCOLS; ++k) {
            minv_r[k] = FLT_MAX; way_r[k] = 0;
            const bool inv = (k == 4) && inval4;
            vmask[k] = inv ? -INFINITY : v_r[k];
            am[k]    = inv ?  INFINITY : 0.f;
        }
        float markg = 0.f;
        int   ent = 0;
        int   j0 = 0, i0 = i;
        float du = 0.f;          // dent - u[i0]; u[i]==0 for a fresh row
        int   jfinal = 0;
        float Dfinal = 0.f;

        // preamble prefetch of row i (overlaps previous row's tail)
        const float* rowp = &s_diag[(i0 - 1) * Qq + lane];
        float c0 = rowp[0], c1 = rowp[64], c2 = rowp[128], c3 = rowp[192],
              c4 = rowp[256];

        while (true) {
            // --- branchless scan over the 5 owned columns ---
            const float cc[KCOLS] = {c0, c1, c2, c3, c4};
            float sv[KCOLS];
#pragma unroll
            for (int k = 0; k < KCOLS; ++k) {
                const float cur = (cc[k] + du) - vmask[k];  // used/invalid -> +inf
                const bool lt = cur < minv_r[k];
                way_r[k]  = lt ? j0  : way_r[k];
                minv_r[k] = lt ? cur : minv_r[k];
                sv[k] = minv_r[k] + am[k];                  // used/invalid -> +inf
            }
            float val = sv[0];
            int   kb  = 0;
#pragma unroll
            for (int k = 1; k < KCOLS; ++k)
                if (sv[k] < val) { val = sv[k]; kb = k; }   // ascending k: min col on tie

            // --- wave argmin; winner's (matched row, col) via one readlane ---
            const float gmin = wave_min_bcast(val);
            const unsigned long long mask = __ballot(val == gmin);
            const int src = __ffsll((long long)mask) - 1;
            const int colid = lane + 1 + (kb << 6);
            const int pk = (sel5i(p_r, kb) << 16) | colid;  // row<=32, col<=300
            const int got = __builtin_amdgcn_readlane(pk, src);
            const int j1   = got & 0xffff;
            const int rowm = got >> 16;

            // mark j1 used at its owner lane (value-mask, no flag array)
            const int k1 = (j1 - 1) >> 6;
            const bool own = (lane == ((j1 - 1) & 63));
#pragma unroll
            for (int k = 0; k < KCOLS; ++k)
                if (own && k == k1) { vmask[k] = -INFINITY; am[k] = INFINITY; }

            if (rowm == 0) { jfinal = j1; Dfinal = gmin; break; }

            // prefetch next row ASAP; bookkeeping runs under the LDS latency
            i0 = rowm; j0 = j1;
            rowp = &s_diag[(i0 - 1) * Qq + lane];
            c0 = rowp[0]; c1 = rowp[64]; c2 = rowp[128]; c3 = rowp[192];
            c4 = rowp[256];
            du = gmin - readlane_f(u_reg, i0);    // dent - u[i0]
            markg = (lane == rowm) ? gmin : markg; // gmin when row entered the tree
            ent   = (lane == rowm) ? 1    : ent;
        }

        // ---- dual updates: pure VALU, no LDS, no fences ----
#pragma unroll
        for (int k = 0; k < KCOLS; ++k) {
            bool usedk = (am[k] == INFINITY);
            if (k == 4) usedk = usedk && !inval4;
            v_r[k] -= usedk ? (Dfinal - minv_r[k]) : 0.f;  // minv frozen at win-gmin
        }
        u_reg += (lane == i) ? Dfinal : (ent ? (Dfinal - markg) : 0.f);

        // ---- augment along the path (readlane walk; few hops) ----
        int jj = jfinal;
        while (jj) {
            const int ow = (jj - 1) & 63, kk = (jj - 1) >> 6;
            const int jprev = __builtin_amdgcn_readlane(sel5i(way_r, kk), ow);
            int pnew;
            if (jprev == 0) pnew = i;
            else pnew = __builtin_amdgcn_readlane(sel5i(p_r, (jprev - 1) >> 6),
                                                  (jprev - 1) & 63);
            const bool own = (lane == ow);
#pragma unroll
            for (int k = 0; k < KCOLS; ++k) if (own && k == kk) p_r[k] = pnew;
            jj = jprev;
        }
    }

    // publish assignment: q_of_t
#pragma unroll
    for (int k = 0; k < KCOLS; ++k)
        if (p_r[k]) pairs[p_r[k] - 1] = lane + 64 * k;
    __threadfence_block();

    // ---------------- Phase C: 32 matched cross costs ----------------
    float part = 0.f;
    if (lane < Tt) {
        const int q = pairs[lane];                        // matched query
        const float* srow = &s_lg[q * LSTRIDE];
        float mx, inv_s;
        softmax_lds(srow, mx, inv_s);                      // identical path to phase A
        const float4 pbv = reinterpret_cast<const float4*>(pboxes)[b * Qq + q];
        const float4 tbv = reinterpret_cast<const float4*>(tboxes)[lane];  // GLOBAL t=lane
        const float cls = -__expf(srow[tlabels[lane]] - mx) * inv_s;
        part = det_cost(pbv.x, pbv.y, pbv.z, pbv.w,
                        tbv.x, tbv.y, tbv.z, tbv.w, cls);
    }
    for (int off = 32; off > 0; off >>= 1) part += __shfl_down(part, off);
    if (lane == 0) atomicAdd(out, part);
}

extern "C" void kernel_launch(void* const* d_in, const int* in_sizes, int n_in,
                              void* d_out, int out_size, void* d_ws, size_t ws_size,
                              hipStream_t stream) {
    const float* logits  = (const float*)d_in[0];   // [32,300,92] f32
    const float* pboxes  = (const float*)d_in[1];   // [32,300,4]  f32
    const int*   tlabels = (const int*)d_in[2];     // [1024]      int
    const float* tboxes  = (const float*)d_in[3];   // [1024,4]    f32
    float* out = (float*)d_out;                     // scalar f32

    hipMemsetAsync(out, 0, sizeof(float), stream);
    const size_t lg_bytes = (size_t)Qq * LSTRIDE * sizeof(float);  // 111600 B
    fused_kernel<<<Nn, 320, lg_bytes, stream>>>(logits, pboxes, tlabels, tboxes, out);
}

// Round 10
// 90.157 us; speedup vs baseline: 1.3103x; 1.1157x over previous
//
#include <hip/hip_runtime.h>
#include <cfloat>
#include <cmath>

// Problem constants (from reference)
#define Nn 32
#define Qq 300
#define Cc 92
#define Tt 32
#define KCOLS 5     // ceil(300/64) columns owned per lane
#define LSTRIDE 93  // LDS logits row stride (dwords); 93%32=29 coprime -> conflict-free

// ---------------------------------------------------------------------------
// DPP full-wave (64-lane) float min, broadcast to all lanes (~6 dep. v_min).
// ---------------------------------------------------------------------------
__device__ inline float wave_min_bcast(float x) {
#define DPPMIN(ctrl) { int _t = __builtin_amdgcn_update_dpp( \
        __float_as_int(x), __float_as_int(x), ctrl, 0xf, 0xf, false); \
        x = fminf(x, __int_as_float(_t)); }
    DPPMIN(0x111) DPPMIN(0x112) DPPMIN(0x114) DPPMIN(0x118)
    DPPMIN(0x142) DPPMIN(0x143)
#undef DPPMIN
    return __int_as_float(__builtin_amdgcn_readlane(__float_as_int(x), 63));
}

// Select a[k] for runtime k (cndmask chain, no scratch).
__device__ inline int sel5i(const int a[KCOLS], int k) {
    int r = a[0];
    if (k == 1) r = a[1];
    if (k == 2) r = a[2];
    if (k == 3) r = a[3];
    if (k == 4) r = a[4];
    return r;
}

__device__ inline float readlane_f(float v, int lane) {
    return __int_as_float(__builtin_amdgcn_readlane(__float_as_int(v), lane));
}

// STREAMING two-pass softmax over an LDS row (no 92-float register array ->
// no scratch spill). Same helper in phase A and C: mx/inv_s bit-identical.
__device__ inline void softmax_lds(const float* __restrict__ srow,
                                   float& mx, float& inv_s) {
    float m = -FLT_MAX;
#pragma unroll
    for (int c = 0; c < Cc; ++c) m = fmaxf(m, srow[c]);
    float s0 = 0.f, s1 = 0.f, s2 = 0.f, s3 = 0.f;
#pragma unroll
    for (int c = 0; c < Cc; c += 4) {
        s0 += __expf(srow[c + 0] - m);
        s1 += __expf(srow[c + 1] - m);
        s2 += __expf(srow[c + 2] - m);
        s3 += __expf(srow[c + 3] - m);
    }
    mx = m; inv_s = 1.f / ((s0 + s1) + (s2 + s3));
}

// cost = 5*L1 + cls - 2*giou   (cls = -softmax_prob[label], passed in)
__device__ inline float det_cost(float cx, float cy, float w, float h,
                                 float bcx, float bcy, float bw, float bh,
                                 float cls) {
    const float ax0 = cx - 0.5f * w, ay0 = cy - 0.5f * h;
    const float ax1 = cx + 0.5f * w, ay1 = cy + 0.5f * h;
    const float areaA = (ax1 - ax0) * (ay1 - ay0);

    const float l1 = fabsf(cx - bcx) + fabsf(cy - bcy) +
                     fabsf(w - bw) + fabsf(h - bh);

    const float bx0 = bcx - 0.5f * bw, by0 = bcy - 0.5f * bh;
    const float bx1 = bcx + 0.5f * bw, by1 = bcy + 0.5f * bh;
    const float areaB = (bx1 - bx0) * (by1 - by0);

    const float ltx = fmaxf(ax0, bx0), lty = fmaxf(ay0, by0);
    const float rbx = fminf(ax1, bx1), rby = fminf(ay1, by1);
    const float iw = fmaxf(rbx - ltx, 0.f), ih = fmaxf(rby - lty, 0.f);
    const float inter = iw * ih;
    const float uni = areaA + areaB - inter;
    const float iou = inter / uni;

    const float ex0 = fminf(ax0, bx0), ey0 = fminf(ay0, by0);
    const float ex1 = fmaxf(ax1, bx1), ey1 = fmaxf(ay1, by1);
    const float areaC = fmaxf(ex1 - ex0, 0.f) * fmaxf(ey1 - ey0, 0.f);
    const float giou = iou - (areaC - uni) / areaC;

    return 5.f * l1 + cls - 2.f * giou;
}

// ---------------------------------------------------------------------------
// Fused kernel: one block per batch.
//  Phase 0: stage logits slice -> LDS (dense coalesced float4).
//  Phase A: diag cost block -> LDS (streaming softmax).
//  Phase B (wave 0): JV LSA with lapjv-style GREEDY ROW-REDUCTION INIT:
//    u[i] = row min, assign argmin col if free (~30/32 rows resolve with zero
//    Dijkstra steps; expected collisions ~32^2/600 ~ 1.7). Remaining rows run
//    the r8 deferred-dual Dijkstra (branchless scan, row prefetch, zero-LDS
//    tail). Duals (u=rowmin, v=0) are feasible + tight on assigned pairs, so
//    the final assignment is the LP optimum = reference's (a.s. unique).
//  Phase C (lanes 0-31): 32 matched CROSS costs (reference quirk:
//    mult[i, q_of_t, arange(T)] gathers against GLOBAL targets 0..31).
// ---------------------------------------------------------------------------
__global__ __launch_bounds__(320) void fused_kernel(
    const float* __restrict__ logits,   // [N,Q,C]
    const float* __restrict__ pboxes,   // [N,Q,4]
    const int*   __restrict__ tlabels,  // [N*T]
    const float* __restrict__ tboxes,   // [N*T,4]
    float* __restrict__ out)            // scalar accumulator (pre-zeroed)
{
    const int b = blockIdx.x;
    const int tid = threadIdx.x;

    extern __shared__ float s_lg[];     // [Qq][LSTRIDE] padded logits, 111600 B
    __shared__ float s_diag[Tt * Qq];   // 38400 B, [t][q]
    __shared__ float s_tb[Tt * 4];      // batch-b targets
    __shared__ int   s_tl[Tt];
    __shared__ int   pairs[Tt];         // q_of_t

    if (tid < Tt * 4) s_tb[tid] = tboxes[b * Tt * 4 + tid];
    if (tid < Tt)     s_tl[tid] = tlabels[b * Tt + tid];

    // ---------------- Phase 0: coalesced logits -> LDS ----------------
    {
        const float4* lgb = reinterpret_cast<const float4*>(
            logits + (size_t)b * Qq * Cc);
#pragma unroll 4
        for (int g = tid; g < Qq * 23; g += 320) {
            const float4 v = lgb[g];
            const int r = g / 23, c4 = (g - r * 23) * 4;
            float* dst = &s_lg[r * LSTRIDE + c4];
            dst[0] = v.x; dst[1] = v.y; dst[2] = v.z; dst[3] = v.w;
        }
    }
    __syncthreads();

    // ---------------- Phase A: diag costs into LDS ----------------
    if (tid < Qq) {
        const float* srow = &s_lg[tid * LSTRIDE];
        float mx, inv_s;
        softmax_lds(srow, mx, inv_s);
        const float4 pbv = reinterpret_cast<const float4*>(pboxes)[b * Qq + tid];
#pragma unroll 4
        for (int t = 0; t < Tt; ++t) {
            const float cls = -__expf(srow[s_tl[t]] - mx) * inv_s;
            s_diag[t * Qq + tid] =
                det_cost(pbv.x, pbv.y, pbv.z, pbv.w,
                         s_tb[t * 4 + 0], s_tb[t * 4 + 1],
                         s_tb[t * 4 + 2], s_tb[t * 4 + 3], cls);
        }
    }
    __syncthreads();      // all 320 threads reach this

    if (tid >= 64) return;            // waves 1-4 done; single wave below
    const int lane = tid;

    // ---------------- Phase B: JV LSA (single wave) ----------------
    float u_reg = 0.f;                // lane t holds u[t] (t=1..32)
    float v_r[KCOLS];
    int p_r[KCOLS];                   // matched row of col (0 = free)
    const bool inval4 = (lane + 256) >= Qq;   // only k=4 can be out of range
#pragma unroll
    for (int k = 0; k < KCOLS; ++k) { v_r[k] = 0.f; p_r[k] = 0; }

    // ---- greedy row-reduction init: u[i]=rowmin, assign argmin col if free
    unsigned int unassigned = 0;      // bit (i-1) set -> row i needs Dijkstra
    {
        const float* rowp = &s_diag[lane];
        float n0 = rowp[0], n1 = rowp[64], n2 = rowp[128], n3 = rowp[192],
              n4 = rowp[256];
        for (int i = 1; i <= Tt; ++i) {
            float m0 = n0, m1 = n1, m2 = n2, m3 = n3, m4 = n4;
            if (i < Tt) {             // prefetch next row under the reduction
                rowp += Qq;
                n0 = rowp[0]; n1 = rowp[64]; n2 = rowp[128]; n3 = rowp[192];
                n4 = rowp[256];
            }
            if (inval4) m4 = INFINITY;
            float val = m0; int kb = 0;
            if (m1 < val) { val = m1; kb = 1; }
            if (m2 < val) { val = m2; kb = 2; }
            if (m3 < val) { val = m3; kb = 3; }
            if (m4 < val) { val = m4; kb = 4; }
            const float gmin = wave_min_bcast(val);
            u_reg = (lane == i) ? gmin : u_reg;          // u[i] = row min
            const unsigned long long mask = __ballot(val == gmin);
            const int src = __ffsll((long long)mask) - 1;
            const int pk = (sel5i(p_r, kb) << 16) | (lane + 1 + (kb << 6));
            const int got = __builtin_amdgcn_readlane(pk, src);
            const int j1 = got & 0xffff, prow = got >> 16;
            if (prow == 0) {          // col free -> assign (tight edge)
                const int k1 = (j1 - 1) >> 6;
                const bool own = (lane == ((j1 - 1) & 63));
#pragma unroll
                for (int k = 0; k < KCOLS; ++k) if (own && k == k1) p_r[k] = i;
            } else {
                unassigned |= 1u << (i - 1);
            }
        }
    }

    // ---- Dijkstra only for collided rows (expected ~2 of 32) ----
    for (unsigned rem = unassigned; rem; rem &= rem - 1) {
        const int i = __ffs(rem);     // row index 1..32

        float minv_r[KCOLS], vmask[KCOLS], am[KCOLS];
        int way_r[KCOLS];
#pragma unroll
        for (int k = 0; k < KCOLS; ++k) {
            minv_r[k] = FLT_MAX; way_r[k] = 0;
            const bool inv = (k == 4) && inval4;
            vmask[k] = inv ? -INFINITY : v_r[k];
            am[k]    = inv ?  INFINITY : 0.f;
        }
        float markg = 0.f;
        int   ent = 0;
        int   j0 = 0, i0 = i;
        float du = 0.f - readlane_f(u_reg, i);   // dent(0) - u[i] (u[i]=rowmin)
        int   jfinal = 0;
        float Dfinal = 0.f;

        // preamble prefetch of row i
        const float* rowp = &s_diag[(i0 - 1) * Qq + lane];
        float c0 = rowp[0], c1 = rowp[64], c2 = rowp[128], c3 = rowp[192],
              c4 = rowp[256];

        while (true) {
            // --- branchless scan over the 5 owned columns ---
            const float cc[KCOLS] = {c0, c1, c2, c3, c4};
            float sv[KCOLS];
#pragma unroll
            for (int k = 0; k < KCOLS; ++k) {
                const float cur = (cc[k] + du) - vmask[k];  // used/invalid -> +inf
                const bool lt = cur < minv_r[k];
                way_r[k]  = lt ? j0  : way_r[k];
                minv_r[k] = lt ? cur : minv_r[k];
                sv[k] = minv_r[k] + am[k];                  // used/invalid -> +inf
            }
            float val = sv[0];
            int   kb  = 0;
#pragma unroll
            for (int k = 1; k < KCOLS; ++k)
                if (sv[k] < val) { val = sv[k]; kb = k; }

            // --- wave argmin; winner's (matched row, col) via one readlane ---
            const float gmin = wave_min_bcast(val);
            const unsigned long long mask = __ballot(val == gmin);
            const int src = __ffsll((long long)mask) - 1;
            const int colid = lane + 1 + (kb << 6);
            const int pk = (sel5i(p_r, kb) << 16) | colid;  // row<=32, col<=300
            const int got = __builtin_amdgcn_readlane(pk, src);
            const int j1   = got & 0xffff;
            const int rowm = got >> 16;

            // mark j1 used (in-tree) at its owner lane (value-mask)
            const int k1 = (j1 - 1) >> 6;
            const bool own = (lane == ((j1 - 1) & 63));
#pragma unroll
            for (int k = 0; k < KCOLS; ++k)
                if (own && k == k1) { vmask[k] = -INFINITY; am[k] = INFINITY; }

            if (rowm == 0) { jfinal = j1; Dfinal = gmin; break; }

            // prefetch next row ASAP; bookkeeping under the LDS latency
            i0 = rowm; j0 = j1;
            rowp = &s_diag[(i0 - 1) * Qq + lane];
            c0 = rowp[0]; c1 = rowp[64]; c2 = rowp[128]; c3 = rowp[192];
            c4 = rowp[256];
            du = gmin - readlane_f(u_reg, i0);     // dent - u[i0]
            markg = (lane == rowm) ? gmin : markg; // dist when row entered tree
            ent   = (lane == rowm) ? 1    : ent;
        }

        // ---- dual updates: pure VALU, no LDS, no fences ----
#pragma unroll
        for (int k = 0; k < KCOLS; ++k) {
            bool usedk = (am[k] == INFINITY);
            if (k == 4) usedk = usedk && !inval4;
            v_r[k] -= usedk ? (Dfinal - minv_r[k]) : 0.f;  // minv frozen at win-gmin
        }
        u_reg += (lane == i) ? Dfinal : (ent ? (Dfinal - markg) : 0.f);

        // ---- augment along the path (readlane walk; few hops) ----
        int jj = jfinal;
        while (jj) {
            const int ow = (jj - 1) & 63, kk = (jj - 1) >> 6;
            const int jprev = __builtin_amdgcn_readlane(sel5i(way_r, kk), ow);
            int pnew;
            if (jprev == 0) pnew = i;
            else pnew = __builtin_amdgcn_readlane(sel5i(p_r, (jprev - 1) >> 6),
                                                  (jprev - 1) & 63);
            const bool own = (lane == ow);
#pragma unroll
            for (int k = 0; k < KCOLS; ++k) if (own && k == kk) p_r[k] = pnew;
            jj = jprev;
        }
    }

    // publish assignment: q_of_t
#pragma unroll
    for (int k = 0; k < KCOLS; ++k)
        if (p_r[k]) pairs[p_r[k] - 1] = lane + 64 * k;
    __threadfence_block();

    // ---------------- Phase C: 32 matched cross costs ----------------
    float part = 0.f;
    if (lane < Tt) {
        const int q = pairs[lane];                        // matched query
        const float* srow = &s_lg[q * LSTRIDE];
        float mx, inv_s;
        softmax_lds(srow, mx, inv_s);                      // identical path to phase A
        const float4 pbv = reinterpret_cast<const float4*>(pboxes)[b * Qq + q];
        const float4 tbv = reinterpret_cast<const float4*>(tboxes)[lane];  // GLOBAL t=lane
        const float cls = -__expf(srow[tlabels[lane]] - mx) * inv_s;
        part = det_cost(pbv.x, pbv.y, pbv.z, pbv.w,
                        tbv.x, tbv.y, tbv.z, tbv.w, cls);
    }
    for (int off = 32; off > 0; off >>= 1) part += __shfl_down(part, off);
    if (lane == 0) atomicAdd(out, part);
}

extern "C" void kernel_launch(void* const* d_in, const int* in_sizes, int n_in,
                              void* d_out, int out_size, void* d_ws, size_t ws_size,
                              hipStream_t stream) {
    const float* logits  = (const float*)d_in[0];   // [32,300,92] f32
    const float* pboxes  = (const float*)d_in[1];   // [32,300,4]  f32
    const int*   tlabels = (const int*)d_in[2];     // [1024]      int
    const float* tboxes  = (const float*)d_in[3];   // [1024,4]    f32
    float* out = (float*)d_out;                     // scalar f32

    (void)hipMemsetAsync(out, 0, sizeof(float), stream);
    const size_t lg_bytes = (size_t)Qq * LSTRIDE * sizeof(float);  // 111600 B
    fused_kernel<<<Nn, 320, lg_bytes, stream>>>(logits, pboxes, tlabels, tboxes, out);
}

// Round 11
// 85.440 us; speedup vs baseline: 1.3826x; 1.0552x over previous
//
#include <hip/hip_runtime.h>
#include <cfloat>
#include <cmath>

// Problem constants (from reference)
#define Nn 32
#define Qq 300
#define Cc 92
#define Tt 32
#define KCOLS 5     // ceil(300/64) columns owned per lane
#define LSTRIDE 93  // LDS logits row stride (dwords); 93%32=29 coprime -> conflict-free

// ---------------------------------------------------------------------------
// DPP full-wave (64-lane) float min, broadcast to all lanes (~6 dep. v_min).
// ---------------------------------------------------------------------------
__device__ inline float wave_min_bcast(float x) {
#define DPPMIN(ctrl) { int _t = __builtin_amdgcn_update_dpp( \
        __float_as_int(x), __float_as_int(x), ctrl, 0xf, 0xf, false); \
        x = fminf(x, __int_as_float(_t)); }
    DPPMIN(0x111) DPPMIN(0x112) DPPMIN(0x114) DPPMIN(0x118)
    DPPMIN(0x142) DPPMIN(0x143)
#undef DPPMIN
    return __int_as_float(__builtin_amdgcn_readlane(__float_as_int(x), 63));
}

// Select a[k] for runtime k (cndmask chain, no scratch).
__device__ inline int sel5i(const int a[KCOLS], int k) {
    int r = a[0];
    if (k == 1) r = a[1];
    if (k == 2) r = a[2];
    if (k == 3) r = a[3];
    if (k == 4) r = a[4];
    return r;
}

__device__ inline float readlane_f(float v, int lane) {
    return __int_as_float(__builtin_amdgcn_readlane(__float_as_int(v), lane));
}

// STREAMING two-pass softmax over an LDS row (no 92-float register array ->
// no scratch spill). Same helper in phase A and C: mx/inv_s bit-identical.
__device__ inline void softmax_lds(const float* __restrict__ srow,
                                   float& mx, float& inv_s) {
    float m = -FLT_MAX;
#pragma unroll
    for (int c = 0; c < Cc; ++c) m = fmaxf(m, srow[c]);
    float s0 = 0.f, s1 = 0.f, s2 = 0.f, s3 = 0.f;
#pragma unroll
    for (int c = 0; c < Cc; c += 4) {
        s0 += __expf(srow[c + 0] - m);
        s1 += __expf(srow[c + 1] - m);
        s2 += __expf(srow[c + 2] - m);
        s3 += __expf(srow[c + 3] - m);
    }
    mx = m; inv_s = 1.f / ((s0 + s1) + (s2 + s3));
}

// cost = 5*L1 + cls - 2*giou   (cls = -softmax_prob[label], passed in)
__device__ inline float det_cost(float cx, float cy, float w, float h,
                                 float bcx, float bcy, float bw, float bh,
                                 float cls) {
    const float ax0 = cx - 0.5f * w, ay0 = cy - 0.5f * h;
    const float ax1 = cx + 0.5f * w, ay1 = cy + 0.5f * h;
    const float areaA = (ax1 - ax0) * (ay1 - ay0);

    const float l1 = fabsf(cx - bcx) + fabsf(cy - bcy) +
                     fabsf(w - bw) + fabsf(h - bh);

    const float bx0 = bcx - 0.5f * bw, by0 = bcy - 0.5f * bh;
    const float bx1 = bcx + 0.5f * bw, by1 = bcy + 0.5f * bh;
    const float areaB = (bx1 - bx0) * (by1 - by0);

    const float ltx = fmaxf(ax0, bx0), lty = fmaxf(ay0, by0);
    const float rbx = fminf(ax1, bx1), rby = fminf(ay1, by1);
    const float iw = fmaxf(rbx - ltx, 0.f), ih = fmaxf(rby - lty, 0.f);
    const float inter = iw * ih;
    const float uni = areaA + areaB - inter;
    const float iou = inter / uni;

    const float ex0 = fminf(ax0, bx0), ey0 = fminf(ay0, by0);
    const float ex1 = fmaxf(ax1, bx1), ey1 = fmaxf(ay1, by1);
    const float areaC = fmaxf(ex1 - ex0, 0.f) * fmaxf(ey1 - ey0, 0.f);
    const float giou = iou - (areaC - uni) / areaC;

    return 5.f * l1 + cls - 2.f * giou;
}

// ---------------------------------------------------------------------------
// Fused kernel: one block per batch.
//  Phase 0: stage logits slice -> LDS (dense coalesced float4).
//  Phase A: diag cost block -> LDS (streaming softmax).
//  Phase A2 (all 5 waves): PARALLEL per-row min+argmin -> s_rowmin/s_rowarg.
//  Phase B (wave 0): u[i]=rowmin; wave-parallel column CLAIM via LDS
//    atomicMin; collided rows resolved by lapjv-style ARR STEAL pass
//    (fresh scan -> m1/j1/m2; free: assign u=m1; taken: u=m2,
//    v[j1]-=m2-m1, steal, requeue old owner). Duals stay feasible, assigned
//    edges tight => optimum = reference's (a.s. unique). Capped; r8
//    deferred-dual Dijkstra as fallback.
//  Phase C (lanes 0-31): 32 matched CROSS costs (reference quirk:
//    mult[i, q_of_t, arange(T)] gathers against GLOBAL targets 0..31).
// ---------------------------------------------------------------------------
__global__ __launch_bounds__(320) void fused_kernel(
    const float* __restrict__ logits,   // [N,Q,C]
    const float* __restrict__ pboxes,   // [N,Q,4]
    const int*   __restrict__ tlabels,  // [N*T]
    const float* __restrict__ tboxes,   // [N*T,4]
    float* __restrict__ out)            // scalar accumulator (pre-zeroed)
{
    const int b = blockIdx.x;
    const int tid = threadIdx.x;

    extern __shared__ float s_lg[];     // [Qq][LSTRIDE] padded logits, 111600 B
    __shared__ float s_diag[Tt * Qq];   // 38400 B, [t][q]
    __shared__ float s_tb[Tt * 4];      // batch-b targets
    __shared__ int   s_tl[Tt];
    __shared__ int   pairs[Tt];         // q_of_t
    __shared__ float s_rowmin[Tt];
    __shared__ int   s_rowarg[Tt];      // 1-based col of row min
    __shared__ int   s_claim[Qq];
    __shared__ int   s_colrow[Qq];      // row id (1..32) matched to col, 0=free

    if (tid < Tt * 4) s_tb[tid] = tboxes[b * Tt * 4 + tid];
    if (tid < Tt)     s_tl[tid] = tlabels[b * Tt + tid];
    if (tid < Qq)     { s_claim[tid] = 1023; s_colrow[tid] = 0; }

    // ---------------- Phase 0: coalesced logits -> LDS ----------------
    {
        const float4* lgb = reinterpret_cast<const float4*>(
            logits + (size_t)b * Qq * Cc);
#pragma unroll 4
        for (int g = tid; g < Qq * 23; g += 320) {
            const float4 v = lgb[g];
            const int r = g / 23, c4 = (g - r * 23) * 4;
            float* dst = &s_lg[r * LSTRIDE + c4];
            dst[0] = v.x; dst[1] = v.y; dst[2] = v.z; dst[3] = v.w;
        }
    }
    __syncthreads();

    // ---------------- Phase A: diag costs into LDS ----------------
    if (tid < Qq) {
        const float* srow = &s_lg[tid * LSTRIDE];
        float mx, inv_s;
        softmax_lds(srow, mx, inv_s);
        const float4 pbv = reinterpret_cast<const float4*>(pboxes)[b * Qq + tid];
#pragma unroll 4
        for (int t = 0; t < Tt; ++t) {
            const float cls = -__expf(srow[s_tl[t]] - mx) * inv_s;
            s_diag[t * Qq + tid] =
                det_cost(pbv.x, pbv.y, pbv.z, pbv.w,
                         s_tb[t * 4 + 0], s_tb[t * 4 + 1],
                         s_tb[t * 4 + 2], s_tb[t * 4 + 3], cls);
        }
    }
    __syncthreads();

    // ------- Phase A2: parallel row-min (wave w handles rows 7w..7w+6) -----
    {
        const int w = tid >> 6, ln = tid & 63;
        const bool iv4 = (ln + 256) >= Qq;
        const int tend = (w * 7 + 7 < Tt) ? (w * 7 + 7) : Tt;
        for (int t = w * 7; t < tend; ++t) {
            const float* rowp = &s_diag[t * Qq + ln];
            float m1 = rowp[0]; int a1 = ln + 1;
            float c;
            c = rowp[64];  if (c < m1) { m1 = c; a1 = ln + 65; }
            c = rowp[128]; if (c < m1) { m1 = c; a1 = ln + 129; }
            c = rowp[192]; if (c < m1) { m1 = c; a1 = ln + 193; }
            c = iv4 ? INFINITY : rowp[256]; if (c < m1) { m1 = c; a1 = ln + 257; }
            const float g = wave_min_bcast(m1);
            const unsigned long long mk = __ballot(m1 == g);
            const int src = __ffsll((long long)mk) - 1;
            const int arg = __builtin_amdgcn_readlane(a1, src);
            if (ln == 0) { s_rowmin[t] = g; s_rowarg[t] = arg; }
        }
    }
    __syncthreads();      // all 320 threads reach this

    if (tid >= 64) return;            // waves 1-4 done; single wave below
    const int lane = tid;
    const bool inval4 = (lane + 256) >= Qq;

    // ---------------- Phase B: claim + ARR + Dijkstra fallback -------------
    float u_reg = (lane >= 1 && lane <= Tt) ? s_rowmin[lane - 1] : 0.f;

    unsigned int rem = 0;             // bit (i-1) -> row i unassigned
    {
        int j = 1, win = 0;
        if (lane < Tt) {
            j = s_rowarg[lane];                    // 1-based col
            atomicMin(&s_claim[j - 1], lane);      // lowest row wins
        }
        if (lane < Tt) {
            win = (s_claim[j - 1] == lane);
            if (win) s_colrow[j - 1] = lane + 1;   // assign col j to row lane+1
        }
        const unsigned long long lost = __ballot((lane < Tt) && !win);
        rem = (unsigned int)lost;
    }
    __threadfence_block();

    float v_r[KCOLS]; int p_r[KCOLS];
#pragma unroll
    for (int k = 0; k < KCOLS; ++k) {
        const int j = lane + 64 * k;
        v_r[k] = 0.f;
        p_r[k] = (j < Qq) ? s_colrow[j] : 0;
    }

    // ---- ARR steal pass: fresh scan per queued row; capped ----
    int pops = 0;
    while (rem && pops < 96) {
        ++pops;
        const int i = __ffs(rem);                  // row 1..32
        rem &= ~(1u << (i - 1));

        const float* rowp = &s_diag[(i - 1) * Qq + lane];
        float m1 = INFINITY, m2 = INFINITY; int a1 = 0, ka = 0;
        float c;
        c = rowp[0]   - v_r[0];
        if (c < m1) { m2 = m1; m1 = c; a1 = lane + 1;   ka = 0; } else if (c < m2) m2 = c;
        c = rowp[64]  - v_r[1];
        if (c < m1) { m2 = m1; m1 = c; a1 = lane + 65;  ka = 1; } else if (c < m2) m2 = c;
        c = rowp[128] - v_r[2];
        if (c < m1) { m2 = m1; m1 = c; a1 = lane + 129; ka = 2; } else if (c < m2) m2 = c;
        c = rowp[192] - v_r[3];
        if (c < m1) { m2 = m1; m1 = c; a1 = lane + 193; ka = 3; } else if (c < m2) m2 = c;
        c = inval4 ? INFINITY : (rowp[256] - v_r[4]);
        if (c < m1) { m2 = m1; m1 = c; a1 = lane + 257; ka = 4; } else if (c < m2) m2 = c;

        const float g1 = wave_min_bcast(m1);
        const unsigned long long mk = __ballot(m1 == g1);
        const int src = __ffsll((long long)mk) - 1;
        const float cand2 = (lane == src) ? m2 : m1;   // global 2nd min excl. j1
        const float g2 = wave_min_bcast(cand2);
        const int pk = (sel5i(p_r, ka) << 16) | a1;    // (owner row, col)
        const int got = __builtin_amdgcn_readlane(pk, src);
        const int j1   = got & 0xffff;
        const int kown = got >> 16;

        u_reg = (lane == i) ? ((kown == 0) ? g1 : g2) : u_reg;

        const int kj = (j1 - 1) >> 6;
        const bool own = (lane == ((j1 - 1) & 63));
        if (kown != 0) {                               // steal: v drop keeps duals ok
#pragma unroll
            for (int k = 0; k < KCOLS; ++k)
                if (own && k == kj) v_r[k] -= (g2 - g1);
            rem |= 1u << (kown - 1);                   // old owner requeued
        }
#pragma unroll
        for (int k = 0; k < KCOLS; ++k)
            if (own && k == kj) p_r[k] = i;
    }

    // ---- Dijkstra fallback (r8 engine) for any remaining rows ----
    for (; rem; rem &= rem - 1) {
        const int i = __ffs(rem);     // row index 1..32

        float minv_r[KCOLS], vmask[KCOLS], am[KCOLS];
        int way_r[KCOLS];
#pragma unroll
        for (int k = 0; k < KCOLS; ++k) {
            minv_r[k] = FLT_MAX; way_r[k] = 0;
            const bool inv = (k == 4) && inval4;
            vmask[k] = inv ? -INFINITY : v_r[k];
            am[k]    = inv ?  INFINITY : 0.f;
        }
        float markg = 0.f;
        int   ent = 0;
        int   j0 = 0, i0 = i;
        float du = 0.f - readlane_f(u_reg, i);   // dent(0) - u[i]
        int   jfinal = 0;
        float Dfinal = 0.f;

        const float* rowp = &s_diag[(i0 - 1) * Qq + lane];
        float c0 = rowp[0], c1 = rowp[64], c2 = rowp[128], c3 = rowp[192],
              c4 = rowp[256];

        while (true) {
            const float cc[KCOLS] = {c0, c1, c2, c3, c4};
            float sv[KCOLS];
#pragma unroll
            for (int k = 0; k < KCOLS; ++k) {
                const float cur = (cc[k] + du) - vmask[k];  // used/invalid -> +inf
                const bool lt = cur < minv_r[k];
                way_r[k]  = lt ? j0  : way_r[k];
                minv_r[k] = lt ? cur : minv_r[k];
                sv[k] = minv_r[k] + am[k];
            }
            float val = sv[0];
            int   kb  = 0;
#pragma unroll
            for (int k = 1; k < KCOLS; ++k)
                if (sv[k] < val) { val = sv[k]; kb = k; }

            const float gmin = wave_min_bcast(val);
            const unsigned long long mask = __ballot(val == gmin);
            const int src = __ffsll((long long)mask) - 1;
            const int colid = lane + 1 + (kb << 6);
            const int pk = (sel5i(p_r, kb) << 16) | colid;
            const int got = __builtin_amdgcn_readlane(pk, src);
            const int j1   = got & 0xffff;
            const int rowm = got >> 16;

            const int k1 = (j1 - 1) >> 6;
            const bool own = (lane == ((j1 - 1) & 63));
#pragma unroll
            for (int k = 0; k < KCOLS; ++k)
                if (own && k == k1) { vmask[k] = -INFINITY; am[k] = INFINITY; }

            if (rowm == 0) { jfinal = j1; Dfinal = gmin; break; }

            i0 = rowm; j0 = j1;
            rowp = &s_diag[(i0 - 1) * Qq + lane];
            c0 = rowp[0]; c1 = rowp[64]; c2 = rowp[128]; c3 = rowp[192];
            c4 = rowp[256];
            du = gmin - readlane_f(u_reg, i0);
            markg = (lane == rowm) ? gmin : markg;
            ent   = (lane == rowm) ? 1    : ent;
        }

#pragma unroll
        for (int k = 0; k < KCOLS; ++k) {
            bool usedk = (am[k] == INFINITY);
            if (k == 4) usedk = usedk && !inval4;
            v_r[k] -= usedk ? (Dfinal - minv_r[k]) : 0.f;
        }
        u_reg += (lane == i) ? Dfinal : (ent ? (Dfinal - markg) : 0.f);

        int jj = jfinal;
        while (jj) {
            const int ow = (jj - 1) & 63, kk = (jj - 1) >> 6;
            const int jprev = __builtin_amdgcn_readlane(sel5i(way_r, kk), ow);
            int pnew;
            if (jprev == 0) pnew = i;
            else pnew = __builtin_amdgcn_readlane(sel5i(p_r, (jprev - 1) >> 6),
                                                  (jprev - 1) & 63);
            const bool own = (lane == ow);
#pragma unroll
            for (int k = 0; k < KCOLS; ++k) if (own && k == kk) p_r[k] = pnew;
            jj = jprev;
        }
    }

    // publish assignment: q_of_t
#pragma unroll
    for (int k = 0; k < KCOLS; ++k)
        if (p_r[k]) pairs[p_r[k] - 1] = lane + 64 * k;
    __threadfence_block();

    // ---------------- Phase C: 32 matched cross costs ----------------
    float part = 0.f;
    if (lane < Tt) {
        const int q = pairs[lane];                        // matched query
        const float* srow = &s_lg[q * LSTRIDE];
        float mx, inv_s;
        softmax_lds(srow, mx, inv_s);                      // identical path to phase A
        const float4 pbv = reinterpret_cast<const float4*>(pboxes)[b * Qq + q];
        const float4 tbv = reinterpret_cast<const float4*>(tboxes)[lane];  // GLOBAL t=lane
        const float cls = -__expf(srow[tlabels[lane]] - mx) * inv_s;
        part = det_cost(pbv.x, pbv.y, pbv.z, pbv.w,
                        tbv.x, tbv.y, tbv.z, tbv.w, cls);
    }
    for (int off = 32; off > 0; off >>= 1) part += __shfl_down(part, off);
    if (lane == 0) atomicAdd(out, part);
}

extern "C" void kernel_launch(void* const* d_in, const int* in_sizes, int n_in,
                              void* d_out, int out_size, void* d_ws, size_t ws_size,
                              hipStream_t stream) {
    const float* logits  = (const float*)d_in[0];   // [32,300,92] f32
    const float* pboxes  = (const float*)d_in[1];   // [32,300,4]  f32
    const int*   tlabels = (const int*)d_in[2];     // [1024]      int
    const float* tboxes  = (const float*)d_in[3];   // [1024,4]    f32
    float* out = (float*)d_out;                     // scalar f32

    (void)hipMemsetAsync(out, 0, sizeof(float), stream);
    const size_t lg_bytes = (size_t)Qq * LSTRIDE * sizeof(float);  // 111600 B
    fused_kernel<<<Nn, 320, lg_bytes, stream>>>(logits, pboxes, tlabels, tboxes, out);
}

// Round 12
// 84.088 us; speedup vs baseline: 1.4048x; 1.0161x over previous
//
#include <hip/hip_runtime.h>
#include <cfloat>
#include <cmath>

// Problem constants (from reference)
#define Nn 32
#define Qq 300
#define Cc 92
#define Tt 32
#define KCOLS 5     // ceil(300/64) columns owned per lane
#define LSTRIDE 93  // LDS logits row stride (dwords); 93%32=29 coprime -> conflict-free

// ---------------------------------------------------------------------------
// DPP full-wave (64-lane) float min, broadcast to all lanes (~6 dep. v_min).
// ---------------------------------------------------------------------------
__device__ inline float wave_min_bcast(float x) {
#define DPPMIN(ctrl) { int _t = __builtin_amdgcn_update_dpp( \
        __float_as_int(x), __float_as_int(x), ctrl, 0xf, 0xf, false); \
        x = fminf(x, __int_as_float(_t)); }
    DPPMIN(0x111) DPPMIN(0x112) DPPMIN(0x114) DPPMIN(0x118)
    DPPMIN(0x142) DPPMIN(0x143)
#undef DPPMIN
    return __int_as_float(__builtin_amdgcn_readlane(__float_as_int(x), 63));
}

// Select a[k] for runtime k (cndmask chain, no scratch).
__device__ inline int sel5i(const int a[KCOLS], int k) {
    int r = a[0];
    if (k == 1) r = a[1];
    if (k == 2) r = a[2];
    if (k == 3) r = a[3];
    if (k == 4) r = a[4];
    return r;
}

__device__ inline float readlane_f(float v, int lane) {
    return __int_as_float(__builtin_amdgcn_readlane(__float_as_int(v), lane));
}

// STREAMING two-pass softmax over an LDS row (no 92-float register array ->
// no scratch spill). Same helper in phase A and C: mx/inv_s bit-identical.
__device__ inline void softmax_lds(const float* __restrict__ srow,
                                   float& mx, float& inv_s) {
    float m = -FLT_MAX;
#pragma unroll
    for (int c = 0; c < Cc; ++c) m = fmaxf(m, srow[c]);
    float s0 = 0.f, s1 = 0.f, s2 = 0.f, s3 = 0.f;
#pragma unroll
    for (int c = 0; c < Cc; c += 4) {
        s0 += __expf(srow[c + 0] - m);
        s1 += __expf(srow[c + 1] - m);
        s2 += __expf(srow[c + 2] - m);
        s3 += __expf(srow[c + 3] - m);
    }
    mx = m; inv_s = 1.f / ((s0 + s1) + (s2 + s3));
}

// cost = 5*L1 + cls - 2*giou   (cls = -softmax_prob[label], passed in)
__device__ inline float det_cost(float cx, float cy, float w, float h,
                                 float bcx, float bcy, float bw, float bh,
                                 float cls) {
    const float ax0 = cx - 0.5f * w, ay0 = cy - 0.5f * h;
    const float ax1 = cx + 0.5f * w, ay1 = cy + 0.5f * h;
    const float areaA = (ax1 - ax0) * (ay1 - ay0);

    const float l1 = fabsf(cx - bcx) + fabsf(cy - bcy) +
                     fabsf(w - bw) + fabsf(h - bh);

    const float bx0 = bcx - 0.5f * bw, by0 = bcy - 0.5f * bh;
    const float bx1 = bcx + 0.5f * bw, by1 = bcy + 0.5f * bh;
    const float areaB = (bx1 - bx0) * (by1 - by0);

    const float ltx = fmaxf(ax0, bx0), lty = fmaxf(ay0, by0);
    const float rbx = fminf(ax1, bx1), rby = fminf(ay1, by1);
    const float iw = fmaxf(rbx - ltx, 0.f), ih = fmaxf(rby - lty, 0.f);
    const float inter = iw * ih;
    const float uni = areaA + areaB - inter;
    const float iou = inter / uni;

    const float ex0 = fminf(ax0, bx0), ey0 = fminf(ay0, by0);
    const float ex1 = fmaxf(ax1, bx1), ey1 = fmaxf(ay1, by1);
    const float areaC = fmaxf(ex1 - ex0, 0.f) * fmaxf(ey1 - ey0, 0.f);
    const float giou = iou - (areaC - uni) / areaC;

    return 5.f * l1 + cls - 2.f * giou;
}

// ---------------------------------------------------------------------------
// Fused kernel: one block per batch.
//  Phase 0: stage logits slice -> LDS (dense coalesced float4).
//  Phase A: diag cost block -> LDS (streaming softmax).
//  Phase B1 (ALL 5 waves): Jacobi PARALLEL AUCTION. Each round, wave w takes
//    the w-th unassigned row; scans its 300 reduced costs (m1/j1/m2); bids
//    delta=m2-m1 on j1 via atomicMax(float-bits+1); winner resolved by
//    atomicMin(row); winner takes col (v[j1]-=delta, u=m2, dethroned owner
//    requeued), losers set u=g1 and requeue. v only decreases; assigned edges
//    stay tight; duals stay feasible (scan-frozen v per round) => on empty
//    queue the matching satisfies complementary slackness => the a.s.-unique
//    LP optimum = reference's assignment. Capped at 64 rounds.
//  Phase B2 (wave 0): r11 deferred-dual Dijkstra fallback for any leftovers
//    (exactness guarantee; normally never triggers).
//  Phase C (lanes 0-31): 32 matched CROSS costs (reference quirk:
//    mult[i, q_of_t, arange(T)] gathers against GLOBAL targets 0..31).
// ---------------------------------------------------------------------------
__global__ __launch_bounds__(320) void fused_kernel(
    const float* __restrict__ logits,   // [N,Q,C]
    const float* __restrict__ pboxes,   // [N,Q,4]
    const int*   __restrict__ tlabels,  // [N*T]
    const float* __restrict__ tboxes,   // [N*T,4]
    float* __restrict__ out)            // scalar accumulator (pre-zeroed)
{
    const int b = blockIdx.x;
    const int tid = threadIdx.x;

    extern __shared__ float s_lg[];     // [Qq][LSTRIDE] padded logits, 111600 B
    __shared__ float s_diag[Tt * Qq];   // 38400 B, [t][q]
    __shared__ float s_tb[Tt * 4];      // batch-b targets
    __shared__ int   s_tl[Tt];
    __shared__ int   pairs[Tt];         // q_of_t
    __shared__ float s_v[Qq];           // column duals
    __shared__ float s_u[Tt + 1];       // row duals (1-based)
    __shared__ int   s_colrow[Qq];      // row (1..32) matched to col, 0=free
    __shared__ unsigned s_bid[Qq];      // float-bits(delta)+1, 0=empty
    __shared__ int   s_bidrow[Qq];      // winning row id per column
    __shared__ unsigned s_mask;         // bit (i-1) -> row i unassigned

    if (tid < Tt * 4) s_tb[tid] = tboxes[b * Tt * 4 + tid];
    if (tid < Tt)     s_tl[tid] = tlabels[b * Tt + tid];
    if (tid < Qq)     { s_v[tid] = 0.f; s_colrow[tid] = 0; }
    if (tid == 0)     s_mask = 0xffffffffu;   // all 32 rows unassigned

    // ---------------- Phase 0: coalesced logits -> LDS ----------------
    {
        const float4* lgb = reinterpret_cast<const float4*>(
            logits + (size_t)b * Qq * Cc);
#pragma unroll 4
        for (int g = tid; g < Qq * 23; g += 320) {
            const float4 v = lgb[g];
            const int r = g / 23, c4 = (g - r * 23) * 4;
            float* dst = &s_lg[r * LSTRIDE + c4];
            dst[0] = v.x; dst[1] = v.y; dst[2] = v.z; dst[3] = v.w;
        }
    }
    __syncthreads();

    // ---------------- Phase A: diag costs into LDS ----------------
    if (tid < Qq) {
        const float* srow = &s_lg[tid * LSTRIDE];
        float mx, inv_s;
        softmax_lds(srow, mx, inv_s);
        const float4 pbv = reinterpret_cast<const float4*>(pboxes)[b * Qq + tid];
#pragma unroll 4
        for (int t = 0; t < Tt; ++t) {
            const float cls = -__expf(srow[s_tl[t]] - mx) * inv_s;
            s_diag[t * Qq + tid] =
                det_cost(pbv.x, pbv.y, pbv.z, pbv.w,
                         s_tb[t * 4 + 0], s_tb[t * 4 + 1],
                         s_tb[t * 4 + 2], s_tb[t * 4 + 3], cls);
        }
    }
    __syncthreads();

    // ------------- Phase B1: parallel auction (all 320 threads) -------------
    {
        const int w = tid >> 6, ln = tid & 63;
        const bool iv4 = (ln + 256) >= Qq;
        for (int round = 0; round < 64; ++round) {
            const unsigned msk = s_mask;        // uniform (read after barrier)
            if (msk == 0) break;                // uniform exit
            if (tid < Qq) { s_bid[tid] = 0u; s_bidrow[tid] = 0xffff; }
            __syncthreads();

            // wave w takes the w-th set bit of msk
            int row = 0;
            { unsigned m = msk; int cnt = w;
              while (m && cnt) { m &= m - 1; --cnt; }
              if (m) row = __ffs(m); }          // 1..32, 0 = idle wave

            float g1 = 0.f, g2 = 0.f; int j1 = 0; unsigned mybid = 0;
            if (row) {
                const float* rowp = &s_diag[(row - 1) * Qq + ln];
                float m1 = INFINITY, m2 = INFINITY; int a1 = 0;
                float c;
                c = rowp[0]   - s_v[ln];
                if (c < m1) { m2 = m1; m1 = c; a1 = ln + 1; }   else if (c < m2) m2 = c;
                c = rowp[64]  - s_v[ln + 64];
                if (c < m1) { m2 = m1; m1 = c; a1 = ln + 65; }  else if (c < m2) m2 = c;
                c = rowp[128] - s_v[ln + 128];
                if (c < m1) { m2 = m1; m1 = c; a1 = ln + 129; } else if (c < m2) m2 = c;
                c = rowp[192] - s_v[ln + 192];
                if (c < m1) { m2 = m1; m1 = c; a1 = ln + 193; } else if (c < m2) m2 = c;
                c = iv4 ? INFINITY : (rowp[256] - s_v[ln + 256]);
                if (c < m1) { m2 = m1; m1 = c; a1 = ln + 257; } else if (c < m2) m2 = c;

                g1 = wave_min_bcast(m1);
                const unsigned long long mk = __ballot(m1 == g1);
                const int src = __ffsll((long long)mk) - 1;
                const float cand2 = (ln == src) ? m2 : m1;  // global 2nd min
                g2 = wave_min_bcast(cand2);
                j1 = __builtin_amdgcn_readlane(a1, src);
                mybid = __float_as_uint(g2 - g1) + 1u;      // delta>=0: bits monotone
                if (ln == 0) atomicMax(&s_bid[j1 - 1], mybid);
            }
            __syncthreads();
            if (row && ln == 0 && s_bid[j1 - 1] == mybid)
                atomicMin(&s_bidrow[j1 - 1], row);
            __syncthreads();
            if (row && ln == 0) {
                if (s_bid[j1 - 1] == mybid && s_bidrow[j1 - 1] == row) {
                    const int old = s_colrow[j1 - 1];       // unique winner/col
                    s_colrow[j1 - 1] = row;
                    s_v[j1 - 1] -= (g2 - g1);
                    s_u[row] = g2;                          // tight + feasible
                    atomicAnd(&s_mask, ~(1u << (row - 1)));
                    if (old) atomicOr(&s_mask, 1u << (old - 1));
                } else {
                    s_u[row] = g1;                          // feasible for fallback
                }
            }
            __syncthreads();
        }
    }

    if (tid >= 64) return;            // waves 1-4 done; wave 0 below
    const int lane = tid;
    const bool inval4 = (lane + 256) >= Qq;

    // load duals/matching into wave-0 registers
    float u_reg = (lane >= 1 && lane <= Tt) ? s_u[lane] : 0.f;
    float v_r[KCOLS]; int p_r[KCOLS];
#pragma unroll
    for (int k = 0; k < KCOLS; ++k) {
        const int j = lane + 64 * k;
        v_r[k] = (j < Qq) ? s_v[j] : 0.f;
        p_r[k] = (j < Qq) ? s_colrow[j] : 0;
    }

    // ---- Phase B2: Dijkstra fallback (r11 engine) for any leftovers ----
    for (unsigned rem = s_mask; rem; rem &= rem - 1) {
        const int i = __ffs(rem);     // row index 1..32

        float minv_r[KCOLS], vmask[KCOLS], am[KCOLS];
        int way_r[KCOLS];
#pragma unroll
        for (int k = 0; k < KCOLS; ++k) {
            minv_r[k] = FLT_MAX; way_r[k] = 0;
            const bool inv = (k == 4) && inval4;
            vmask[k] = inv ? -INFINITY : v_r[k];
            am[k]    = inv ?  INFINITY : 0.f;
        }
        float markg = 0.f;
        int   ent = 0;
        int   j0 = 0, i0 = i;
        float du = 0.f - readlane_f(u_reg, i);   // dent(0) - u[i]
        int   jfinal = 0;
        float Dfinal = 0.f;

        const float* rowp = &s_diag[(i0 - 1) * Qq + lane];
        float c0 = rowp[0], c1 = rowp[64], c2 = rowp[128], c3 = rowp[192],
              c4 = rowp[256];

        while (true) {
            const float cc[KCOLS] = {c0, c1, c2, c3, c4};
            float sv[KCOLS];
#pragma unroll
            for (int k = 0; k < KCOLS; ++k) {
                const float cur = (cc[k] + du) - vmask[k];  // used/invalid -> +inf
                const bool lt = cur < minv_r[k];
                way_r[k]  = lt ? j0  : way_r[k];
                minv_r[k] = lt ? cur : minv_r[k];
                sv[k] = minv_r[k] + am[k];
            }
            float val = sv[0];
            int   kb  = 0;
#pragma unroll
            for (int k = 1; k < KCOLS; ++k)
                if (sv[k] < val) { val = sv[k]; kb = k; }

            const float gmin = wave_min_bcast(val);
            const unsigned long long mask = __ballot(val == gmin);
            const int src = __ffsll((long long)mask) - 1;
            const int colid = lane + 1 + (kb << 6);
            const int pk = (sel5i(p_r, kb) << 16) | colid;
            const int got = __builtin_amdgcn_readlane(pk, src);
            const int j1   = got & 0xffff;
            const int rowm = got >> 16;

            const int k1 = (j1 - 1) >> 6;
            const bool own = (lane == ((j1 - 1) & 63));
#pragma unroll
            for (int k = 0; k < KCOLS; ++k)
                if (own && k == k1) { vmask[k] = -INFINITY; am[k] = INFINITY; }

            if (rowm == 0) { jfinal = j1; Dfinal = gmin; break; }

            i0 = rowm; j0 = j1;
            rowp = &s_diag[(i0 - 1) * Qq + lane];
            c0 = rowp[0]; c1 = rowp[64]; c2 = rowp[128]; c3 = rowp[192];
            c4 = rowp[256];
            du = gmin - readlane_f(u_reg, i0);
            markg = (lane == rowm) ? gmin : markg;
            ent   = (lane == rowm) ? 1    : ent;
        }

#pragma unroll
        for (int k = 0; k < KCOLS; ++k) {
            bool usedk = (am[k] == INFINITY);
            if (k == 4) usedk = usedk && !inval4;
            v_r[k] -= usedk ? (Dfinal - minv_r[k]) : 0.f;
        }
        u_reg += (lane == i) ? Dfinal : (ent ? (Dfinal - markg) : 0.f);

        int jj = jfinal;
        while (jj) {
            const int ow = (jj - 1) & 63, kk = (jj - 1) >> 6;
            const int jprev = __builtin_amdgcn_readlane(sel5i(way_r, kk), ow);
            int pnew;
            if (jprev == 0) pnew = i;
            else pnew = __builtin_amdgcn_readlane(sel5i(p_r, (jprev - 1) >> 6),
                                                  (jprev - 1) & 63);
            const bool own = (lane == ow);
#pragma unroll
            for (int k = 0; k < KCOLS; ++k) if (own && k == kk) p_r[k] = pnew;
            jj = jprev;
        }
    }

    // publish assignment: q_of_t
#pragma unroll
    for (int k = 0; k < KCOLS; ++k)
        if (p_r[k]) pairs[p_r[k] - 1] = lane + 64 * k;
    __threadfence_block();

    // ---------------- Phase C: 32 matched cross costs ----------------
    float part = 0.f;
    if (lane < Tt) {
        const int q = pairs[lane];                        // matched query
        const float* srow = &s_lg[q * LSTRIDE];
        float mx, inv_s;
        softmax_lds(srow, mx, inv_s);                      // identical path to phase A
        const float4 pbv = reinterpret_cast<const float4*>(pboxes)[b * Qq + q];
        const float4 tbv = reinterpret_cast<const float4*>(tboxes)[lane];  // GLOBAL t=lane
        const float cls = -__expf(srow[tlabels[lane]] - mx) * inv_s;
        part = det_cost(pbv.x, pbv.y, pbv.z, pbv.w,
                        tbv.x, tbv.y, tbv.z, tbv.w, cls);
    }
    for (int off = 32; off > 0; off >>= 1) part += __shfl_down(part, off);
    if (lane == 0) atomicAdd(out, part);
}

extern "C" void kernel_launch(void* const* d_in, const int* in_sizes, int n_in,
                              void* d_out, int out_size, void* d_ws, size_t ws_size,
                              hipStream_t stream) {
    const float* logits  = (const float*)d_in[0];   // [32,300,92] f32
    const float* pboxes  = (const float*)d_in[1];   // [32,300,4]  f32
    const int*   tlabels = (const int*)d_in[2];     // [1024]      int
    const float* tboxes  = (const float*)d_in[3];   // [1024,4]    f32
    float* out = (float*)d_out;                     // scalar f32

    (void)hipMemsetAsync(out, 0, sizeof(float), stream);
    const size_t lg_bytes = (size_t)Qq * LSTRIDE * sizeof(float);  // 111600 B
    fused_kernel<<<Nn, 320, lg_bytes, stream>>>(logits, pboxes, tlabels, tboxes, out);
}